// Round 13
// baseline (273.406 us; speedup 1.0000x reference)
//
#include <hip/hip_runtime.h>
#include <math.h>

#define B_   16
#define V_   16
#define C_   64
#define M_   32
#define CM_  16
#define D_   128
#define OUT_ 600
#define NSEQ 256      // B*V
#define NROW 8192     // B*V*M

typedef __attribute__((ext_vector_type(8))) short bf16x8;
typedef __attribute__((ext_vector_type(4))) short bf16x4;
typedef __attribute__((ext_vector_type(4))) float f32x4;

__device__ __forceinline__ unsigned short f2bf(float x) {
  union { float f; unsigned u; } v; v.f = x;
  unsigned r = v.u + 0x7fff + ((v.u >> 16) & 1);   // RNE
  return (unsigned short)(r >> 16);
}
__device__ __forceinline__ float bf2f(short s) {
  union { unsigned u; float f; } v;
  v.u = ((unsigned)(unsigned short)s) << 16;
  return v.f;
}
// fast sigmoid / tanh: native v_exp + v_rcp (~5 inst), saturate correctly
__device__ __forceinline__ float fsig(float x)  { return __fdividef(1.f, 1.f + __expf(-x)); }
__device__ __forceinline__ float ftanh(float x) { return 1.f - 2.f*__fdividef(1.f, __expf(2.f*x) + 1.f); }

// LDS-only barrier: drains LDS ops for cross-wave visibility but does NOT
// drain vmcnt — in-flight global prefetch loads survive the barrier.
__device__ __forceinline__ void ldsbar() {
  asm volatile("s_waitcnt lgkmcnt(0)" ::: "memory");
  __builtin_amdgcn_s_barrier();
  asm volatile("" ::: "memory");
}

// ---- workspace layout (float units; bf16 arrays are short* views) ----
constexpr int OFF_VISB  = 98304;                           // bf16 [3][256][128]
constexpr int OFF_MONB  = 147456;                           // bf16 [2][8192][128]
constexpr int OFF_W12T  = 2244608;                          // bf16 [8][128n][256k]
constexpr int OFF_WIHB  = 2375680;                          // bf16 [5][384n][128k]
constexpr int OFF_CNT   = 2498560;                          // int [16] run counters
constexpr int OFF_XE    = 2695168;                          // fp32 [2][256][128]
constexpr int OFF_LAST  = 27926528;                         // fp32 [8][256][128]
constexpr int OFF_VH    = 29171712;                         // fp32 [10][16][128]

// =====================================================================
// prep+vis+mon merged — wihTv branch removed (legacy); block 0 also
// zeros the run counters used by k_ggru's in-kernel vgru handoff.
// =====================================================================
__global__ __launch_bounds__(256) void k_prepvis(
    const float* __restrict__ Wself, const float* __restrict__ Wmsg,
    const float* __restrict__ mWih,
    const float* __restrict__ wgt,   const float* __restrict__ age,
    const float* __restrict__ fwW,   const float* __restrict__ fwB,
    const float* __restrict__ faW,   const float* __restrict__ faB,
    const int* __restrict__ cc, const int* __restrict__ cp, const int* __restrict__ cd,
    const float* __restrict__ ec, const float* __restrict__ ep, const float* __restrict__ ed,
    const int* __restrict__ cli, const int* __restrict__ clv,
    const int* __restrict__ cii, const int* __restrict__ civ,
    const float* __restrict__ eli, const float* __restrict__ elv,
    const float* __restrict__ eii, const float* __restrict__ eiv,
    short* __restrict__ w12t, short* __restrict__ wihb,
    float* __restrict__ xe,
    short* __restrict__ visb, short* __restrict__ monb,
    int* __restrict__ cnt)
{
  int bx = blockIdx.x, tid = threadIdx.x;
  if (bx < 1024) {                      // w12t[pt][n][k] = bf16 combined
    if (bx == 0 && tid < 16) cnt[tid] = 0;   // zero handoff counters
    int lin = bx*256 + tid;             // < 262144
    int pt = lin >> 15, rem = lin & 32767;
    int n = rem >> 8, k = rem & 255;
    float v;
    if (k < 128) v = Wself[pt*16384 + k*128 + n] - Wmsg[pt*16384 + k*128 + n]*(1.f/3.f);
    else         v = Wmsg[pt*16384 + (k-128)*128 + n]*(1.f/3.f);
    w12t[lin] = (short)f2bf(v);
  } else if (bx < 1984) {               // wihb = bf16(mWih) elementwise
    int lin = (bx-1024)*256 + tid;      // < 245760
    wihb[lin] = (short)f2bf(mWih[lin]);
  } else if (bx < 2240) {               // xe for weight / age
    int lin = (bx-1984)*256 + tid;      // < 65536
    int which = lin >> 15, rem2 = lin & 32767;
    int n = rem2 >> 7, d = rem2 & 127;
    float x  = which ? age[n] : wgt[n];
    float Wv = which ? faW[d] : fwW[d];
    float bb = which ? faB[d] : fwB[d];
    xe[lin] = (x != 0.0f) ? (x*Wv + bb) : 0.0f;
  } else if (bx < 2624) {               // visit-event sum pools -> visb
    int idx = (bx-2240)*256 + tid;      // < 98304
    int type = idx >> 15;
    int r = idx & 32767;
    int bv = r >> 7, d = r & 127;
    const int*   codes = (type==0) ? cc : (type==1) ? cp : cd;
    const float* emb   = (type==0) ? ec : (type==1) ? ep : ed;
    float acc = 0.f;
    for (int c = 0; c < C_; ++c) {
      int code = codes[bv*C_ + c];
      acc += emb[code*D_ + d];
    }
    visb[(type*NSEQ + bv)*D_ + d] = (short)f2bf(acc);
  } else {                              // merged k_mon: monb only
    int rowid = (bx-2624)*2 + (tid >> 7);   // 0..16383
    int p = rowid >> 13, bvm = rowid & 8191;
    int d = tid & 127;
    const int* ci = p ? cii : cli;  const int* cv = p ? civ : clv;
    const float* ei = p ? eii : eli; const float* ev = p ? eiv : elv;
    float acc = 0.f;
    #pragma unroll
    for (int c2 = 0; c2 < CM_; ++c2) {
      int iv = ci[bvm*CM_ + c2];
      int vv = cv[bvm*CM_ + c2];
      acc += ei[iv*D_ + d] * ev[vv*D_ + d];
    }
    monb[((size_t)p*NROW + bvm)*D_ + d] = (short)f2bf(acc);
  }
}

// =====================================================================
// FUSED GNN+GI+monitor-GRU + visit-GRU (k_ggru v3) — THIS ROUND:
// the k_vgru dispatch is absorbed. Blocks 0..127 run the verified v2.2
// ggru; after writing `last`, release-fence + device atomicAdd(cnt[run]);
// the 16th arriver runs the verified vgru-v4 body for that run in-place.
// Blocks 128/129 run vgru for xe-runs 8/9 concurrently with ggru.
// Cross-XCD visibility: __threadfence release/acquire around the atomic.
// =====================================================================
__global__ __launch_bounds__(512, 1) void k_ggru(
    const short* __restrict__ monb, const short* __restrict__ visb,
    const short* __restrict__ w12t, const short* __restrict__ wihb,
    const float* __restrict__ Wself, const float* __restrict__ mWhh,
    const float* __restrict__ mbih, const float* __restrict__ mbhh,
    const float* __restrict__ vWih, const float* __restrict__ vWhh,
    const float* __restrict__ vbih, const float* __restrict__ vbhh,
    const float* __restrict__ xe, float* __restrict__ last,
    float* __restrict__ vh, int* __restrict__ cnt)
{
  const int tid = threadIdx.x;
  const int w = tid >> 6;               // wave 0..7
  const int lane = tid & 63;
  const int c = lane & 15, q = lane >> 4;
  const int j = w*16 + c;               // hidden index 0..127

  __shared__ short hb[2][4][16][40];            // 10240 B (verified layout)
  __shared__ __align__(16) short Ys[2][16][136];// 8704 B
  __shared__ __align__(16) short Xl[2][2048];   // 8192 B
  __shared__ int dofin;

  int vrun;

  if (blockIdx.x < 128) {
    const int run  = blockIdx.x >> 4;   // 0..7
    const int pair = blockIdx.x & 15;   // batch b
    const int p = run >> 2, t = run & 3;
    const int g = (run % 4 == 0) ? (run / 4) : (run % 4 + 1);

    for (int idx = tid; idx < 2*4*16*40; idx += 512)
      ((short*)hb)[idx] = 0;

    // ---- W12 frags ----
    bf16x8 bW12[8];
    #pragma unroll
    for (int kt = 0; kt < 8; ++kt)
      bW12[kt] = *(const bf16x8*)(w12t + (size_t)run*32768 + (size_t)j*256 + kt*32 + q*8);

    // ---- steady stage1 B-frags: Ws = (t==0 ? Wself exact : W2) ----
    bf16x8 bWs[4];
    if (t == 0) {
      const float* wsp = Wself + (size_t)run*16384 + j;    // + k*128
      #pragma unroll
      for (int kt = 0; kt < 4; ++kt) {
        bf16x8 tt;
        #pragma unroll
        for (int i = 0; i < 8; ++i)
          tt[i] = (short)f2bf(wsp[(kt*32 + q*8 + i)*128]);
        bWs[kt] = tt;
      }
    } else {
      #pragma unroll
      for (int kt = 0; kt < 4; ++kt) bWs[kt] = bW12[kt+4];
    }

    // ---- Cpre: step-invariant part of Y ----
    f32x4 Cpre = (f32x4){0.f,0.f,0.f,0.f};
    {
      const int bvc = pair*16 + c;
      #pragma unroll
      for (int kt = 0; kt < 4; ++kt) {
        const int ko = kt*32 + q*8;
        bf16x8 v0 = *(const bf16x8*)(visb + (size_t)(0*NSEQ + bvc)*128 + ko);
        bf16x8 v1 = *(const bf16x8*)(visb + (size_t)(1*NSEQ + bvc)*128 + ko);
        bf16x8 v2 = *(const bf16x8*)(visb + (size_t)(2*NSEQ + bvc)*128 + ko);
        bf16x8 vs;
        #pragma unroll
        for (int i = 0; i < 8; ++i)
          vs[i] = (short)f2bf(bf2f(v0[i]) + bf2f(v1[i]) + bf2f(v2[i]));
        Cpre = __builtin_amdgcn_mfma_f32_16x16x32_bf16(vs, bW12[kt+4], Cpre, 0, 0, 0);
      }
      if (t > 0) {
        #pragma unroll
        for (int kt = 0; kt < 4; ++kt) {
          const int ko = kt*32 + q*8;
          bf16x8 fv = *(const bf16x8*)(visb + (size_t)((t-1)*NSEQ + bvc)*128 + ko);
          Cpre = __builtin_amdgcn_mfma_f32_16x16x32_bf16(fv, bW12[kt], Cpre, 0, 0, 0);
        }
      }
    }

    // ---- stage2/3 B-frags ----
    bf16x8 bWih[3][4];
    #pragma unroll
    for (int gate = 0; gate < 3; ++gate)
      #pragma unroll
      for (int kt = 0; kt < 4; ++kt)
        bWih[gate][kt] = *(const bf16x8*)(wihb + ((size_t)g*384 + gate*128 + j)*128 + kt*32 + q*8);

    bf16x8 bWhh[3][4];
    #pragma unroll
    for (int gate = 0; gate < 3; ++gate) {
      const float* wp = mWhh + ((size_t)g*384 + gate*128 + j)*128 + q*8;
      #pragma unroll
      for (int kt = 0; kt < 4; ++kt) {
        float4 lo = *(const float4*)(wp + kt*32);
        float4 hi = *(const float4*)(wp + kt*32 + 4);
        bf16x8 tt;
        tt[0]=(short)f2bf(lo.x); tt[1]=(short)f2bf(lo.y); tt[2]=(short)f2bf(lo.z); tt[3]=(short)f2bf(lo.w);
        tt[4]=(short)f2bf(hi.x); tt[5]=(short)f2bf(hi.y); tt[6]=(short)f2bf(hi.z); tt[7]=(short)f2bf(hi.w);
        bWhh[gate][kt] = tt;
      }
    }
    const float bs0 = mbih[g*384 +       j] + mbhh[g*384 +       j];
    const float bs1 = mbih[g*384 + 128 + j] + mbhh[g*384 + 128 + j];
    const float bi2 = mbih[g*384 + 256 + j];
    const float bh2 = mbhh[g*384 + 256 + j];

    // ---- mon staging ----
    const bool stg = (tid < 256);
    const int xr_ = (tid >> 4) & 15, xu = tid & 15;
    const int bv = pair*16 + xr_;
    const short* fsrc = monb + ((size_t)p*NROW + (size_t)bv*32)*128 + xu*8;
    const int xdofs = xr_*128 + (((xu*16) ^ ((xr_&7)<<4)) >> 1);
    short* xdst0 = &Xl[0][xdofs];
    short* xdst1 = &Xl[1][xdofs];

    if (stg) {
      *(bf16x8*)xdst0 = *(const bf16x8*)fsrc;
      *(bf16x8*)xdst1 = *(const bf16x8*)(fsrc + 128);
    }
    float hf[4] = {0.f,0.f,0.f,0.f};
    const int ktw = w >> 1;
    const int kkw = (w & 1)*16 + c;
    ldsbar();

    // prologue stage1: Y(0)
    {
      const char* xbase = (const char*)&Xl[0][0];
      f32x4 accY = Cpre;
      #pragma unroll
      for (int kt = 0; kt < 4; ++kt) {
        bf16x8 aX = *(const bf16x8*)(xbase + c*256 + ((kt*64 + q*16) ^ ((c&7)<<4)));
        accY = __builtin_amdgcn_mfma_f32_16x16x32_bf16(aX, bWs[kt], accY, 0, 0, 0);
      }
      #pragma unroll
      for (int reg = 0; reg < 4; ++reg)
        Ys[0][q*4 + reg][w*16 + c] = (short)f2bf(fmaxf(accY[reg], 0.f));
    }
    ldsbar();

    #pragma unroll 1
    for (int m = 0; m < 32; ++m) {
      const int cur = m & 1, nxt = cur ^ 1;
      bf16x8 xnext;
      if (stg && m < 30) xnext = *(const bf16x8*)(fsrc + (size_t)(m+2)*128);

      f32x4 accY = Cpre;
      if (m < 31) {
        const char* xbase = (const char*)&Xl[nxt][0];
        #pragma unroll
        for (int kt = 0; kt < 4; ++kt) {
          bf16x8 aX = *(const bf16x8*)(xbase + c*256 + ((kt*64 + q*16) ^ ((c&7)<<4)));
          accY = __builtin_amdgcn_mfma_f32_16x16x32_bf16(aX, bWs[kt], accY, 0, 0, 0);
        }
      }

      bf16x8 ah[4], a2[4];
      #pragma unroll
      for (int kt = 0; kt < 4; ++kt) {
        ah[kt] = *(const bf16x8*)&hb[cur][kt][c][q*8];
        a2[kt] = *(const bf16x8*)&Ys[cur][c][kt*32 + q*8];
      }
      f32x4 acc0 = (f32x4){0.f,0.f,0.f,0.f};
      f32x4 acc1 = (f32x4){0.f,0.f,0.f,0.f};
      f32x4 aG2  = (f32x4){0.f,0.f,0.f,0.f};
      f32x4 aH2  = (f32x4){0.f,0.f,0.f,0.f};
      #pragma unroll
      for (int kt = 0; kt < 4; ++kt) {
        acc0 = __builtin_amdgcn_mfma_f32_16x16x32_bf16(ah[kt], bWhh[0][kt], acc0, 0, 0, 0);
        acc1 = __builtin_amdgcn_mfma_f32_16x16x32_bf16(ah[kt], bWhh[1][kt], acc1, 0, 0, 0);
        aH2  = __builtin_amdgcn_mfma_f32_16x16x32_bf16(ah[kt], bWhh[2][kt], aH2,  0, 0, 0);
      }
      #pragma unroll
      for (int kt = 0; kt < 4; ++kt) {
        acc0 = __builtin_amdgcn_mfma_f32_16x16x32_bf16(a2[kt], bWih[0][kt], acc0, 0, 0, 0);
        acc1 = __builtin_amdgcn_mfma_f32_16x16x32_bf16(a2[kt], bWih[1][kt], acc1, 0, 0, 0);
        aG2  = __builtin_amdgcn_mfma_f32_16x16x32_bf16(a2[kt], bWih[2][kt], aG2,  0, 0, 0);
      }

      if (m < 31) {
        #pragma unroll
        for (int reg = 0; reg < 4; ++reg)
          Ys[nxt][q*4 + reg][w*16 + c] = (short)f2bf(fmaxf(accY[reg], 0.f));
      }
      if (stg && m < 30) *(bf16x8*)(cur ? xdst1 : xdst0) = xnext;

      #pragma unroll
      for (int reg = 0; reg < 4; ++reg) {
        float rr = fsig(acc0[reg] + bs0);
        float zz = fsig(acc1[reg] + bs1);
        float nn = ftanh(aG2[reg] + bi2 + rr*(aH2[reg] + bh2));
        float hnew = (1.f - zz)*nn + zz*hf[reg];
        hf[reg] = hnew;
        hb[nxt][ktw][q*4 + reg][kkw] = (short)f2bf(hnew);
      }
      ldsbar();
    }

    #pragma unroll
    for (int reg = 0; reg < 4; ++reg)
      last[((size_t)run*NSEQ + pair*16 + q*4 + reg)*D_ + j] = hf[reg];

    // ---- handoff: 16th arriver for this run becomes the vgru finisher ----
    __threadfence();                         // release last-writes
    if (tid == 0) {
      int old = atomicAdd(&cnt[run], 1);     // device-scope
      dofin = (old == 15) ? 1 : 0;
    }
    __syncthreads();
    if (!dofin) return;
    __threadfence();                         // acquire other blocks' last
    vrun = run;
  } else {
    vrun = 8 + ((int)blockIdx.x - 128);      // xe-based runs, no wait
  }

  // ===================== visit-GRU (verified v4 body) =====================
  {
    const int vidx = (vrun < 4) ? 0 : (vrun < 8) ? 1 : (vrun - 6);

    for (int idx = tid; idx < 2*4*16*40; idx += 512)
      ((short*)hb)[idx] = 0;

    bf16x8 vWihF[3][4], vWhhF[3][4];
    #pragma unroll
    for (int gate = 0; gate < 3; ++gate) {
      const float* wi = vWih + ((size_t)vidx*384 + gate*128 + j)*128 + q*8;
      const float* wh = vWhh + ((size_t)vidx*384 + gate*128 + j)*128 + q*8;
      #pragma unroll
      for (int kt = 0; kt < 4; ++kt) {
        float4 a0 = *(const float4*)(wi + kt*32);
        float4 a1 = *(const float4*)(wi + kt*32 + 4);
        float4 b0 = *(const float4*)(wh + kt*32);
        float4 b1 = *(const float4*)(wh + kt*32 + 4);
        bf16x8 ti, th;
        ti[0]=(short)f2bf(a0.x); ti[1]=(short)f2bf(a0.y); ti[2]=(short)f2bf(a0.z); ti[3]=(short)f2bf(a0.w);
        ti[4]=(short)f2bf(a1.x); ti[5]=(short)f2bf(a1.y); ti[6]=(short)f2bf(a1.z); ti[7]=(short)f2bf(a1.w);
        th[0]=(short)f2bf(b0.x); th[1]=(short)f2bf(b0.y); th[2]=(short)f2bf(b0.z); th[3]=(short)f2bf(b0.w);
        th[4]=(short)f2bf(b1.x); th[5]=(short)f2bf(b1.y); th[6]=(short)f2bf(b1.z); th[7]=(short)f2bf(b1.w);
        vWihF[gate][kt] = ti;
        vWhhF[gate][kt] = th;
      }
    }
    const float vs0 = vbih[vidx*384 +       j] + vbhh[vidx*384 +       j];
    const float vs1 = vbih[vidx*384 + 128 + j] + vbhh[vidx*384 + 128 + j];
    const float vi2 = vbih[vidx*384 + 256 + j];
    const float vh2 = vbhh[vidx*384 + 256 + j];

    const bool stg = (tid < 256);
    const int xr_ = (tid >> 4) & 15, xu = tid & 15;
    const float* xsrc = ((vrun < 8) ? (last + ((size_t)vrun*NSEQ + xr_*16)*D_)
                                    : (xe + ((size_t)(vrun-8)*NSEQ + xr_*16)*D_)) + xu*8;
    const int xdofs = xr_*128 + (((xu*16) ^ ((xr_&7)<<4)) >> 1);
    short* xdst0 = &Xl[0][xdofs];
    short* xdst1 = &Xl[1][xdofs];

    auto stageX = [&](short* dst, int v) {
      const float* s = xsrc + (size_t)v*D_;
      float4 lo = *(const float4*)s;
      float4 hi = *(const float4*)(s + 4);
      bf16x8 t2;
      t2[0]=(short)f2bf(lo.x); t2[1]=(short)f2bf(lo.y); t2[2]=(short)f2bf(lo.z); t2[3]=(short)f2bf(lo.w);
      t2[4]=(short)f2bf(hi.x); t2[5]=(short)f2bf(hi.y); t2[6]=(short)f2bf(hi.z); t2[7]=(short)f2bf(hi.w);
      *(bf16x8*)dst = t2;
    };
    if (stg) { stageX(xdst0, 0); stageX(xdst1, 1); }

    float hf[4] = {0.f,0.f,0.f,0.f};
    const int ktw = w >> 1;
    const int kkw = (w & 1)*16 + c;
    ldsbar();   // hb zeros + X(0), X(1) visible

    f32x4 giA[3], giB[3];
    {
      const char* xbase = (const char*)&Xl[0][0];
      #pragma unroll
      for (int gate = 0; gate < 3; ++gate) giA[gate] = (f32x4){0.f,0.f,0.f,0.f};
      #pragma unroll
      for (int kt = 0; kt < 4; ++kt) {
        bf16x8 ax = *(const bf16x8*)(xbase + c*256 + ((kt*64 + q*16) ^ ((c&7)<<4)));
        giA[0] = __builtin_amdgcn_mfma_f32_16x16x32_bf16(ax, vWihF[0][kt], giA[0], 0, 0, 0);
        giA[1] = __builtin_amdgcn_mfma_f32_16x16x32_bf16(ax, vWihF[1][kt], giA[1], 0, 0, 0);
        giA[2] = __builtin_amdgcn_mfma_f32_16x16x32_bf16(ax, vWihF[2][kt], giA[2], 0, 0, 0);
      }
    }
    ldsbar();

    auto step = [&](int v, f32x4 (&gcur)[3], f32x4 (&gnext)[3]) {
      const int cur = v & 1, nxt = cur ^ 1;
      if (v < 15) {
        const char* xbase = (const char*)&Xl[nxt][0];
        #pragma unroll
        for (int gate = 0; gate < 3; ++gate) gnext[gate] = (f32x4){0.f,0.f,0.f,0.f};
        #pragma unroll
        for (int kt = 0; kt < 4; ++kt) {
          bf16x8 ax = *(const bf16x8*)(xbase + c*256 + ((kt*64 + q*16) ^ ((c&7)<<4)));
          gnext[0] = __builtin_amdgcn_mfma_f32_16x16x32_bf16(ax, vWihF[0][kt], gnext[0], 0, 0, 0);
          gnext[1] = __builtin_amdgcn_mfma_f32_16x16x32_bf16(ax, vWihF[1][kt], gnext[1], 0, 0, 0);
          gnext[2] = __builtin_amdgcn_mfma_f32_16x16x32_bf16(ax, vWihF[2][kt], gnext[2], 0, 0, 0);
        }
      }
      bf16x8 ah[4];
      #pragma unroll
      for (int kt = 0; kt < 4; ++kt)
        ah[kt] = *(const bf16x8*)&hb[cur][kt][c][q*8];
      f32x4 a0 = gcur[0], a1 = gcur[1];
      f32x4 aH2 = (f32x4){0.f,0.f,0.f,0.f};
      #pragma unroll
      for (int kt = 0; kt < 4; ++kt) {
        a0  = __builtin_amdgcn_mfma_f32_16x16x32_bf16(ah[kt], vWhhF[0][kt], a0,  0, 0, 0);
        a1  = __builtin_amdgcn_mfma_f32_16x16x32_bf16(ah[kt], vWhhF[1][kt], a1,  0, 0, 0);
        aH2 = __builtin_amdgcn_mfma_f32_16x16x32_bf16(ah[kt], vWhhF[2][kt], aH2, 0, 0, 0);
      }
      if (stg && v < 14) stageX(cur ? xdst1 : xdst0, v + 2);
      #pragma unroll
      for (int reg = 0; reg < 4; ++reg) {
        float rr = fsig(a0[reg] + vs0);
        float zz = fsig(a1[reg] + vs1);
        float nn = ftanh(gcur[2][reg] + vi2 + rr*(aH2[reg] + vh2));
        float hnew = (1.f - zz)*nn + zz*hf[reg];
        hf[reg] = hnew;
        hb[nxt][ktw][q*4 + reg][kkw] = (short)f2bf(hnew);
      }
      ldsbar();
    };

    #pragma unroll 1
    for (int v2 = 0; v2 < 8; ++v2) {
      step(2*v2,     giA, giB);
      step(2*v2 + 1, giB, giA);
    }

    #pragma unroll
    for (int reg = 0; reg < 4; ++reg)
      vh[((size_t)vrun*16 + q*4 + reg)*D_ + j] = hf[reg];
  }
}

// =====================================================================
// head v4 (pe fused) — verified, unchanged.
// =====================================================================
__global__ __launch_bounds__(256) void k_head(
    const float* __restrict__ vh, const float* __restrict__ Wp,
    const float* __restrict__ bp, float* __restrict__ out)
{
  const int o = blockIdx.x;
  const int tid = threadIdx.x;
  const int b = tid & 15, kc = tid >> 4;
  const int a1[7] = {0,1,2,3,4,8,9};
  const int a2[7] = {-1,5,6,7,-1,-1,-1};
  const float4* wb = (const float4*)(Wp + (size_t)o*896 + kc*56);
  float acc = 0.f;
  #pragma unroll
  for (int i = 0; i < 14; ++i) {
    int cc2 = kc*56 + i*4;
    int s = cc2 >> 7, d0 = cc2 & 127;
    float4 a = *(const float4*)(vh + (a1[s]*16 + b)*D_ + d0);
    int s2 = a2[s];
    if (s2 >= 0) {
      float4 a2v = *(const float4*)(vh + (s2*16 + b)*D_ + d0);
      a.x += a2v.x; a.y += a2v.y; a.z += a2v.z; a.w += a2v.w;
    }
    a.x = fmaxf(a.x, 0.f); a.y = fmaxf(a.y, 0.f);
    a.z = fmaxf(a.z, 0.f); a.w = fmaxf(a.w, 0.f);
    float4 ww = wb[i];
    acc += a.x*ww.x + a.y*ww.y + a.z*ww.z + a.w*ww.w;
  }
  __shared__ float red[16][17];
  red[kc][b] = acc;
  __syncthreads();
  if (tid < 16) {
    float s = 0.f;
    #pragma unroll
    for (int k = 0; k < 16; ++k) s += red[k][tid];
    out[tid*OUT_ + o] = s + bp[o];
  }
}

// =====================================================================
extern "C" void kernel_launch(void* const* d_in, const int* in_sizes, int n_in,
                              void* d_out, int out_size, void* d_ws, size_t ws_size,
                              hipStream_t stream)
{
  (void)in_sizes; (void)n_in; (void)out_size; (void)ws_size;
  const int*   cc   = (const int*)  d_in[0];
  const int*   cp   = (const int*)  d_in[1];
  const int*   cd   = (const int*)  d_in[2];
  const int*   cli  = (const int*)  d_in[3];
  const int*   clv  = (const int*)  d_in[4];
  const int*   cii  = (const int*)  d_in[5];
  const int*   civ  = (const int*)  d_in[6];
  const float* wgt  = (const float*)d_in[7];
  const float* age  = (const float*)d_in[8];
  const float* ec   = (const float*)d_in[9];
  const float* ep   = (const float*)d_in[10];
  const float* ed   = (const float*)d_in[11];
  const float* eli  = (const float*)d_in[12];
  const float* elv  = (const float*)d_in[13];
  const float* eii  = (const float*)d_in[14];
  const float* eiv  = (const float*)d_in[15];
  const float* mWih = (const float*)d_in[16];
  const float* mWhh = (const float*)d_in[17];
  const float* mbih = (const float*)d_in[18];
  const float* mbhh = (const float*)d_in[19];
  const float* vWih = (const float*)d_in[20];
  const float* vWhh = (const float*)d_in[21];
  const float* vbih = (const float*)d_in[22];
  const float* vbhh = (const float*)d_in[23];
  const float* Wself= (const float*)d_in[24];
  const float* Wmsg = (const float*)d_in[25];
  const float* fwW  = (const float*)d_in[26];
  const float* fwB  = (const float*)d_in[27];
  const float* faW  = (const float*)d_in[28];
  const float* faB  = (const float*)d_in[29];
  const float* Wp   = (const float*)d_in[30];
  const float* bp   = (const float*)d_in[31];
  float* out = (float*)d_out;
  float* ws  = (float*)d_ws;

  short* visb  = (short*)(ws + OFF_VISB);
  short* monb  = (short*)(ws + OFF_MONB);
  short* w12t  = (short*)(ws + OFF_W12T);
  short* wihb  = (short*)(ws + OFF_WIHB);
  int*   cnt   = (int*)  (ws + OFF_CNT);
  float* xe    = ws + OFF_XE;
  float* last  = ws + OFF_LAST;
  float* vh    = ws + OFF_VH;

  k_prepvis<<<10816, 256, 0, stream>>>(Wself, Wmsg, mWih, wgt, age,
                                       fwW, fwB, faW, faB,
                                       cc, cp, cd, ec, ep, ed,
                                       cli, clv, cii, civ, eli, elv, eii, eiv,
                                       w12t, wihb, xe, visb, monb, cnt);
  k_ggru<<<130, 512, 0, stream>>>(monb, visb, w12t, wihb, Wself,
                                  mWhh, mbih, mbhh,
                                  vWih, vWhh, vbih, vbhh,
                                  xe, last, vh, cnt);
  k_head<<<600, 256, 0, stream>>>(vh, Wp, bp, out);
}

// Round 14
// 245.124 us; speedup vs baseline: 1.1154x; 1.1154x over previous
//
#include <hip/hip_runtime.h>
#include <math.h>

#define B_   16
#define V_   16
#define C_   64
#define M_   32
#define CM_  16
#define D_   128
#define OUT_ 600
#define NSEQ 256      // B*V
#define NROW 8192     // B*V*M

typedef __attribute__((ext_vector_type(8))) short bf16x8;
typedef __attribute__((ext_vector_type(4))) short bf16x4;
typedef __attribute__((ext_vector_type(4))) float f32x4;

__device__ __forceinline__ unsigned short f2bf(float x) {
  union { float f; unsigned u; } v; v.f = x;
  unsigned r = v.u + 0x7fff + ((v.u >> 16) & 1);   // RNE
  return (unsigned short)(r >> 16);
}
__device__ __forceinline__ float bf2f(short s) {
  union { unsigned u; float f; } v;
  v.u = ((unsigned)(unsigned short)s) << 16;
  return v.f;
}
// fast sigmoid / tanh: native v_exp + v_rcp (~5 inst), saturate correctly
__device__ __forceinline__ float fsig(float x)  { return __fdividef(1.f, 1.f + __expf(-x)); }
__device__ __forceinline__ float ftanh(float x) { return 1.f - 2.f*__fdividef(1.f, __expf(2.f*x) + 1.f); }

// LDS-only barrier: drains LDS ops for cross-wave visibility but does NOT
// drain vmcnt — in-flight global prefetch loads survive the barrier.
__device__ __forceinline__ void ldsbar() {
  asm volatile("s_waitcnt lgkmcnt(0)" ::: "memory");
  __builtin_amdgcn_s_barrier();
  asm volatile("" ::: "memory");
}

// ---- workspace layout (float units; bf16 arrays are short* views) ----
constexpr int OFF_VISB  = 98304;                           // bf16 [3][256][128]
constexpr int OFF_MONB  = 147456;                           // bf16 [2][8192][128]
constexpr int OFF_W12T  = 2244608;                          // bf16 [8][128n][256k]
constexpr int OFF_WIHB  = 2375680;                          // bf16 [5][384n][128k]
constexpr int OFF_XE    = 2695168;                          // fp32 [2][256][128]
constexpr int OFF_LAST  = 27926528;                         // fp32 [8][256][128]
constexpr int OFF_VH    = 29171712;                         // fp32 [10][16][128]

// =====================================================================
// prep+vis+mon merged — round-13 form (wihTv branch deleted), cnt
// logic removed (handoff reverted). 10816 blocks.
// =====================================================================
__global__ __launch_bounds__(256) void k_prepvis(
    const float* __restrict__ Wself, const float* __restrict__ Wmsg,
    const float* __restrict__ mWih,
    const float* __restrict__ wgt,   const float* __restrict__ age,
    const float* __restrict__ fwW,   const float* __restrict__ fwB,
    const float* __restrict__ faW,   const float* __restrict__ faB,
    const int* __restrict__ cc, const int* __restrict__ cp, const int* __restrict__ cd,
    const float* __restrict__ ec, const float* __restrict__ ep, const float* __restrict__ ed,
    const int* __restrict__ cli, const int* __restrict__ clv,
    const int* __restrict__ cii, const int* __restrict__ civ,
    const float* __restrict__ eli, const float* __restrict__ elv,
    const float* __restrict__ eii, const float* __restrict__ eiv,
    short* __restrict__ w12t, short* __restrict__ wihb,
    float* __restrict__ xe,
    short* __restrict__ visb, short* __restrict__ monb)
{
  int bx = blockIdx.x, tid = threadIdx.x;
  if (bx < 1024) {                      // w12t[pt][n][k] = bf16 combined
    int lin = bx*256 + tid;             // < 262144
    int pt = lin >> 15, rem = lin & 32767;
    int n = rem >> 8, k = rem & 255;
    float v;
    if (k < 128) v = Wself[pt*16384 + k*128 + n] - Wmsg[pt*16384 + k*128 + n]*(1.f/3.f);
    else         v = Wmsg[pt*16384 + (k-128)*128 + n]*(1.f/3.f);
    w12t[lin] = (short)f2bf(v);
  } else if (bx < 1984) {               // wihb = bf16(mWih) elementwise
    int lin = (bx-1024)*256 + tid;      // < 245760
    wihb[lin] = (short)f2bf(mWih[lin]);
  } else if (bx < 2240) {               // xe for weight / age
    int lin = (bx-1984)*256 + tid;      // < 65536
    int which = lin >> 15, rem2 = lin & 32767;
    int n = rem2 >> 7, d = rem2 & 127;
    float x  = which ? age[n] : wgt[n];
    float Wv = which ? faW[d] : fwW[d];
    float bb = which ? faB[d] : fwB[d];
    xe[lin] = (x != 0.0f) ? (x*Wv + bb) : 0.0f;
  } else if (bx < 2624) {               // visit-event sum pools -> visb
    int idx = (bx-2240)*256 + tid;      // < 98304
    int type = idx >> 15;
    int r = idx & 32767;
    int bv = r >> 7, d = r & 127;
    const int*   codes = (type==0) ? cc : (type==1) ? cp : cd;
    const float* emb   = (type==0) ? ec : (type==1) ? ep : ed;
    float acc = 0.f;
    for (int c = 0; c < C_; ++c) {
      int code = codes[bv*C_ + c];
      acc += emb[code*D_ + d];
    }
    visb[(type*NSEQ + bv)*D_ + d] = (short)f2bf(acc);
  } else {                              // merged k_mon: monb only
    int rowid = (bx-2624)*2 + (tid >> 7);   // 0..16383
    int p = rowid >> 13, bvm = rowid & 8191;
    int d = tid & 127;
    const int* ci = p ? cii : cli;  const int* cv = p ? civ : clv;
    const float* ei = p ? eii : eli; const float* ev = p ? eiv : elv;
    float acc = 0.f;
    #pragma unroll
    for (int c2 = 0; c2 < CM_; ++c2) {
      int iv = ci[bvm*CM_ + c2];
      int vv = cv[bvm*CM_ + c2];
      acc += ei[iv*D_ + d] * ev[vv*D_ + d];
    }
    monb[((size_t)p*NROW + bvm)*D_ + d] = (short)f2bf(acc);
  }
}

// =====================================================================
// FUSED GNN+GI+monitor-GRU (k_ggru v2.3) — REVERTED to verified v2.2
// (round 10/11, 64.5 us) + phase-B chain split: acc0/acc1 become two
// independent 4-deep MFMA chains (Whh-part, Wih-part) summed in VALU
// at activation — halves MFMA dependency depth on the critical path.
// =====================================================================
__global__ __launch_bounds__(512, 1) void k_ggru(
    const short* __restrict__ monb, const short* __restrict__ visb,
    const short* __restrict__ w12t, const short* __restrict__ wihb,
    const float* __restrict__ Wself, const float* __restrict__ mWhh,
    const float* __restrict__ mbih, const float* __restrict__ mbhh,
    float* __restrict__ last)
{
  const int run  = blockIdx.x >> 4;     // 0..7
  const int pair = blockIdx.x & 15;     // batch b
  const int p = run >> 2, t = run & 3;
  const int g = (run % 4 == 0) ? (run / 4) : (run % 4 + 1);
  const int tid = threadIdx.x;
  const int w = tid >> 6;               // wave 0..7 = hidden slice
  const int lane = tid & 63;
  const int c = lane & 15, q = lane >> 4;
  const int j = w*16 + c;               // hidden index 0..127

  __shared__ short hb[2][4][16][40];            // 10240 B (v8-verified layout)
  __shared__ __align__(16) short Ys[2][16][136];// 8704 B (double-buffered)
  __shared__ __align__(16) short Xl[2][2048];   // 8192 B (mon rows only)

  for (int idx = tid; idx < 2*4*16*40; idx += 512)
    ((short*)hb)[idx] = 0;

  // ---- W12 frags (prologue use; W2 half also steady for t>0) ----
  bf16x8 bW12[8];
  #pragma unroll
  for (int kt = 0; kt < 8; ++kt)
    bW12[kt] = *(const bf16x8*)(w12t + (size_t)run*32768 + (size_t)j*256 + kt*32 + q*8);

  // ---- steady stage1 B-frags: Ws = (t==0 ? Wself exact : W2) ----
  bf16x8 bWs[4];
  if (t == 0) {
    const float* wsp = Wself + (size_t)run*16384 + j;    // + k*128
    #pragma unroll
    for (int kt = 0; kt < 4; ++kt) {
      bf16x8 tt;
      #pragma unroll
      for (int i = 0; i < 8; ++i)
        tt[i] = (short)f2bf(wsp[(kt*32 + q*8 + i)*128]);
      bWs[kt] = tt;
    }
  } else {
    #pragma unroll
    for (int kt = 0; kt < 4; ++kt) bWs[kt] = bW12[kt+4];
  }

  // ---- Cpre: step-invariant part of Y, computed once ----
  f32x4 Cpre = (f32x4){0.f,0.f,0.f,0.f};
  {
    const int bvc = pair*16 + c;
    #pragma unroll
    for (int kt = 0; kt < 4; ++kt) {
      const int ko = kt*32 + q*8;
      bf16x8 v0 = *(const bf16x8*)(visb + (size_t)(0*NSEQ + bvc)*128 + ko);
      bf16x8 v1 = *(const bf16x8*)(visb + (size_t)(1*NSEQ + bvc)*128 + ko);
      bf16x8 v2 = *(const bf16x8*)(visb + (size_t)(2*NSEQ + bvc)*128 + ko);
      bf16x8 vs;
      #pragma unroll
      for (int i = 0; i < 8; ++i)
        vs[i] = (short)f2bf(bf2f(v0[i]) + bf2f(v1[i]) + bf2f(v2[i]));
      Cpre = __builtin_amdgcn_mfma_f32_16x16x32_bf16(vs, bW12[kt+4], Cpre, 0, 0, 0);
    }
    if (t > 0) {
      #pragma unroll
      for (int kt = 0; kt < 4; ++kt) {
        const int ko = kt*32 + q*8;
        bf16x8 fv = *(const bf16x8*)(visb + (size_t)((t-1)*NSEQ + bvc)*128 + ko);
        Cpre = __builtin_amdgcn_mfma_f32_16x16x32_bf16(fv, bW12[kt], Cpre, 0, 0, 0);
      }
    }
  }

  // ---- stage2 B-frags: wihb rows gate*128+j ----
  bf16x8 bWih[3][4];
  #pragma unroll
  for (int gate = 0; gate < 3; ++gate)
    #pragma unroll
    for (int kt = 0; kt < 4; ++kt)
      bWih[gate][kt] = *(const bf16x8*)(wihb + ((size_t)g*384 + gate*128 + j)*128 + kt*32 + q*8);

  // ---- stage3 B-frags: mWhh rows gate*128+j (fp32 -> bf16) ----
  bf16x8 bWhh[3][4];
  #pragma unroll
  for (int gate = 0; gate < 3; ++gate) {
    const float* wp = mWhh + ((size_t)g*384 + gate*128 + j)*128 + q*8;
    #pragma unroll
    for (int kt = 0; kt < 4; ++kt) {
      float4 lo = *(const float4*)(wp + kt*32);
      float4 hi = *(const float4*)(wp + kt*32 + 4);
      bf16x8 tt;
      tt[0]=(short)f2bf(lo.x); tt[1]=(short)f2bf(lo.y); tt[2]=(short)f2bf(lo.z); tt[3]=(short)f2bf(lo.w);
      tt[4]=(short)f2bf(hi.x); tt[5]=(short)f2bf(hi.y); tt[6]=(short)f2bf(hi.z); tt[7]=(short)f2bf(hi.w);
      bWhh[gate][kt] = tt;
    }
  }
  const float bs0 = mbih[g*384 +       j] + mbhh[g*384 +       j];
  const float bs1 = mbih[g*384 + 128 + j] + mbhh[g*384 + 128 + j];
  const float bi2 = mbih[g*384 + 256 + j];
  const float bh2 = mbhh[g*384 + 256 + j];

  // ---- mon staging: 256 threads, 16 rows x 16 slots x 8 shorts ----
  const bool stg = (tid < 256);
  const int xr_ = (tid >> 4) & 15, xu = tid & 15;   // valid when stg
  const int bv = pair*16 + xr_;
  const short* fsrc = monb + ((size_t)p*NROW + (size_t)bv*32)*128 + xu*8;
  const int xdofs = xr_*128 + (((xu*16) ^ ((xr_&7)<<4)) >> 1);   // shorts
  short* xdst0 = &Xl[0][xdofs];
  short* xdst1 = &Xl[1][xdofs];

  // prologue: mon(0) -> Xl[0], mon(1) -> Xl[1]
  if (stg) {
    *(bf16x8*)xdst0 = *(const bf16x8*)fsrc;
    *(bf16x8*)xdst1 = *(const bf16x8*)(fsrc + 128);
  }
  float hf[4] = {0.f,0.f,0.f,0.f};
  const int ktw = w >> 1;               // j>>5
  const int kkw = (w & 1)*16 + c;       // j&31
  ldsbar();   // hb zero + X(0), X(1) visible

  // prologue stage1: Y(0) from Xl[0] -> Ys[0]
  {
    const char* xbase = (const char*)&Xl[0][0];
    f32x4 accY = Cpre;
    #pragma unroll
    for (int kt = 0; kt < 4; ++kt) {
      bf16x8 aX = *(const bf16x8*)(xbase + c*256 + ((kt*64 + q*16) ^ ((c&7)<<4)));
      accY = __builtin_amdgcn_mfma_f32_16x16x32_bf16(aX, bWs[kt], accY, 0, 0, 0);
    }
    #pragma unroll
    for (int reg = 0; reg < 4; ++reg)
      Ys[0][q*4 + reg][w*16 + c] = (short)f2bf(fmaxf(accY[reg], 0.f));
  }
  ldsbar();   // Ys[0] ready

  #pragma unroll 1
  for (int m = 0; m < 32; ++m) {
    const int cur = m & 1, nxt = cur ^ 1;

    // issue mon(m+2) global load early (hidden under this step)
    bf16x8 xnext;
    if (stg && m < 30) xnext = *(const bf16x8*)(fsrc + (size_t)(m+2)*128);

    // ---- phase A: stage1 for step m+1: Y(m+1) = Cpre + mon@Ws^T ----
    f32x4 accY = Cpre;
    if (m < 31) {
      const char* xbase = (const char*)&Xl[nxt][0];
      #pragma unroll
      for (int kt = 0; kt < 4; ++kt) {
        bf16x8 aX = *(const bf16x8*)(xbase + c*256 + ((kt*64 + q*16) ^ ((c&7)<<4)));
        accY = __builtin_amdgcn_mfma_f32_16x16x32_bf16(aX, bWs[kt], accY, 0, 0, 0);
      }
    }

    // ---- phase B: stage2+3 gate pre-acts from Ys[cur], hb[cur] ----
    // chain-split: Whh-part and Wih-part accumulate independently
    bf16x8 ah[4], a2[4];
    #pragma unroll
    for (int kt = 0; kt < 4; ++kt) {
      ah[kt] = *(const bf16x8*)&hb[cur][kt][c][q*8];
      a2[kt] = *(const bf16x8*)&Ys[cur][c][kt*32 + q*8];
    }
    f32x4 a0h = (f32x4){0.f,0.f,0.f,0.f}, a0i = (f32x4){0.f,0.f,0.f,0.f};
    f32x4 a1h = (f32x4){0.f,0.f,0.f,0.f}, a1i = (f32x4){0.f,0.f,0.f,0.f};
    f32x4 aG2 = (f32x4){0.f,0.f,0.f,0.f}, aH2 = (f32x4){0.f,0.f,0.f,0.f};
    #pragma unroll
    for (int kt = 0; kt < 4; ++kt) {
      a0h = __builtin_amdgcn_mfma_f32_16x16x32_bf16(ah[kt], bWhh[0][kt], a0h, 0, 0, 0);
      a0i = __builtin_amdgcn_mfma_f32_16x16x32_bf16(a2[kt], bWih[0][kt], a0i, 0, 0, 0);
      a1h = __builtin_amdgcn_mfma_f32_16x16x32_bf16(ah[kt], bWhh[1][kt], a1h, 0, 0, 0);
      a1i = __builtin_amdgcn_mfma_f32_16x16x32_bf16(a2[kt], bWih[1][kt], a1i, 0, 0, 0);
      aH2 = __builtin_amdgcn_mfma_f32_16x16x32_bf16(ah[kt], bWhh[2][kt], aH2, 0, 0, 0);
      aG2 = __builtin_amdgcn_mfma_f32_16x16x32_bf16(a2[kt], bWih[2][kt], aG2, 0, 0, 0);
    }

    // write Y(m+1) into Ys[nxt] (read at step m+1, after the barrier)
    if (m < 31) {
      #pragma unroll
      for (int reg = 0; reg < 4; ++reg)
        Ys[nxt][q*4 + reg][w*16 + c] = (short)f2bf(fmaxf(accY[reg], 0.f));
    }
    // write mon(m+2) into Xl[cur] (its old contents consumed at step m-1)
    if (stg && m < 30) *(bf16x8*)(cur ? xdst1 : xdst0) = xnext;

    // ---- lane-local GRU activation: (seq = q*4+reg, this j) ----
    #pragma unroll
    for (int reg = 0; reg < 4; ++reg) {
      float rr = fsig(a0h[reg] + a0i[reg] + bs0);
      float zz = fsig(a1h[reg] + a1i[reg] + bs1);
      float nn = ftanh(aG2[reg] + bi2 + rr*(aH2[reg] + bh2));
      float hnew = (1.f - zz)*nn + zz*hf[reg];
      hf[reg] = hnew;
      hb[nxt][ktw][q*4 + reg][kkw] = (short)f2bf(hnew);
    }
    ldsbar();   // ONE barrier: Ys[nxt] + hb[nxt] + Xl[cur] visible for m+1
  }

  #pragma unroll
  for (int reg = 0; reg < 4; ++reg)
    last[((size_t)run*NSEQ + pair*16 + q*4 + reg)*D_ + j] = hf[reg];
}

// =====================================================================
// visit-level GRU v4 — verified round 11, unchanged (separate dispatch
// restored; round-12 handoff merge reverted).
// =====================================================================
__global__ __launch_bounds__(512, 1) void k_vgru(
    const float* __restrict__ last, const float* __restrict__ xe,
    const float* __restrict__ vWih, const float* __restrict__ vWhh,
    const float* __restrict__ vbih, const float* __restrict__ vbhh,
    float* __restrict__ vh)
{
  const int run = blockIdx.x;           // 0..9
  const int vidx = (run < 4) ? 0 : (run < 8) ? 1 : (run - 6);
  const int tid = threadIdx.x;
  const int w = tid >> 6;               // wave 0..7 = hidden slice
  const int lane = tid & 63;
  const int c = lane & 15, q = lane >> 4;
  const int j = w*16 + c;               // hidden index 0..127

  __shared__ short hb[2][4][16][40];            // 10240 B (verified layout)
  __shared__ __align__(16) short Xl[2][2048];   // 8192 B, XOR-swizzled rows

  for (int idx = tid; idx < 2*4*16*40; idx += 512)
    ((short*)hb)[idx] = 0;

  // ---- weight frags: vWih/vWhh rows gate*128+j (fp32 -> bf16) ----
  bf16x8 bWih[3][4], bWhh[3][4];
  #pragma unroll
  for (int gate = 0; gate < 3; ++gate) {
    const float* wi = vWih + ((size_t)vidx*384 + gate*128 + j)*128 + q*8;
    const float* wh = vWhh + ((size_t)vidx*384 + gate*128 + j)*128 + q*8;
    #pragma unroll
    for (int kt = 0; kt < 4; ++kt) {
      float4 a0 = *(const float4*)(wi + kt*32);
      float4 a1 = *(const float4*)(wi + kt*32 + 4);
      float4 b0 = *(const float4*)(wh + kt*32);
      float4 b1 = *(const float4*)(wh + kt*32 + 4);
      bf16x8 ti, th;
      ti[0]=(short)f2bf(a0.x); ti[1]=(short)f2bf(a0.y); ti[2]=(short)f2bf(a0.z); ti[3]=(short)f2bf(a0.w);
      ti[4]=(short)f2bf(a1.x); ti[5]=(short)f2bf(a1.y); ti[6]=(short)f2bf(a1.z); ti[7]=(short)f2bf(a1.w);
      th[0]=(short)f2bf(b0.x); th[1]=(short)f2bf(b0.y); th[2]=(short)f2bf(b0.z); th[3]=(short)f2bf(b0.w);
      th[4]=(short)f2bf(b1.x); th[5]=(short)f2bf(b1.y); th[6]=(short)f2bf(b1.z); th[7]=(short)f2bf(b1.w);
      bWih[gate][kt] = ti;
      bWhh[gate][kt] = th;
    }
  }
  const float bs0 = vbih[vidx*384 +       j] + vbhh[vidx*384 +       j];
  const float bs1 = vbih[vidx*384 + 128 + j] + vbhh[vidx*384 + 128 + j];
  const float bi2 = vbih[vidx*384 + 256 + j];
  const float bh2 = vbhh[vidx*384 + 256 + j];

  // ---- X staging: 256 threads, 16 rows (batches) x 16 slots x 8 f32 ----
  const bool stg = (tid < 256);
  const int xr_ = (tid >> 4) & 15, xu = tid & 15;
  const float* xsrc = ((run < 8) ? (last + ((size_t)run*NSEQ + xr_*16)*D_)
                                 : (xe + ((size_t)(run-8)*NSEQ + xr_*16)*D_)) + xu*8;
  const int xdofs = xr_*128 + (((xu*16) ^ ((xr_&7)<<4)) >> 1);   // shorts
  short* xdst0 = &Xl[0][xdofs];
  short* xdst1 = &Xl[1][xdofs];

  auto stageX = [&](short* dst, int v) {
    const float* s = xsrc + (size_t)v*D_;
    float4 lo = *(const float4*)s;
    float4 hi = *(const float4*)(s + 4);
    bf16x8 t;
    t[0]=(short)f2bf(lo.x); t[1]=(short)f2bf(lo.y); t[2]=(short)f2bf(lo.z); t[3]=(short)f2bf(lo.w);
    t[4]=(short)f2bf(hi.x); t[5]=(short)f2bf(hi.y); t[6]=(short)f2bf(hi.z); t[7]=(short)f2bf(hi.w);
    *(bf16x8*)dst = t;
  };
  if (stg) { stageX(xdst0, 0); stageX(xdst1, 1); }

  float hf[4] = {0.f,0.f,0.f,0.f};
  const int ktw = w >> 1;               // j>>5
  const int kkw = (w & 1)*16 + c;       // j&31
  ldsbar();   // hb zeros + X(0), X(1) visible

  // prologue: gi(0) from Xl[0] into registers (no relay needed)
  f32x4 giA[3], giB[3];
  {
    const char* xbase = (const char*)&Xl[0][0];
    #pragma unroll
    for (int gate = 0; gate < 3; ++gate) giA[gate] = (f32x4){0.f,0.f,0.f,0.f};
    #pragma unroll
    for (int kt = 0; kt < 4; ++kt) {
      bf16x8 ax = *(const bf16x8*)(xbase + c*256 + ((kt*64 + q*16) ^ ((c&7)<<4)));
      giA[0] = __builtin_amdgcn_mfma_f32_16x16x32_bf16(ax, bWih[0][kt], giA[0], 0, 0, 0);
      giA[1] = __builtin_amdgcn_mfma_f32_16x16x32_bf16(ax, bWih[1][kt], giA[1], 0, 0, 0);
      giA[2] = __builtin_amdgcn_mfma_f32_16x16x32_bf16(ax, bWih[2][kt], giA[2], 0, 0, 0);
    }
  }
  ldsbar();   // all waves done reading Xl[0] before step 0 overwrites it

  auto step = [&](int v, f32x4 (&gcur)[3], f32x4 (&gnext)[3]) {
    const int cur = v & 1, nxt = cur ^ 1;
    // phase A: gi(v+1) from Xl[nxt] (register carry, no relay)
    if (v < 15) {
      const char* xbase = (const char*)&Xl[nxt][0];
      #pragma unroll
      for (int gate = 0; gate < 3; ++gate) gnext[gate] = (f32x4){0.f,0.f,0.f,0.f};
      #pragma unroll
      for (int kt = 0; kt < 4; ++kt) {
        bf16x8 ax = *(const bf16x8*)(xbase + c*256 + ((kt*64 + q*16) ^ ((c&7)<<4)));
        gnext[0] = __builtin_amdgcn_mfma_f32_16x16x32_bf16(ax, bWih[0][kt], gnext[0], 0, 0, 0);
        gnext[1] = __builtin_amdgcn_mfma_f32_16x16x32_bf16(ax, bWih[1][kt], gnext[1], 0, 0, 0);
        gnext[2] = __builtin_amdgcn_mfma_f32_16x16x32_bf16(ax, bWih[2][kt], gnext[2], 0, 0, 0);
      }
    }
    // phase B: gh(v) from hb[cur], seeded with carried gi(v)
    bf16x8 ah[4];
    #pragma unroll
    for (int kt = 0; kt < 4; ++kt)
      ah[kt] = *(const bf16x8*)&hb[cur][kt][c][q*8];
    f32x4 a0 = gcur[0], a1 = gcur[1];
    f32x4 aH2 = (f32x4){0.f,0.f,0.f,0.f};
    #pragma unroll
    for (int kt = 0; kt < 4; ++kt) {
      a0  = __builtin_amdgcn_mfma_f32_16x16x32_bf16(ah[kt], bWhh[0][kt], a0,  0, 0, 0);
      a1  = __builtin_amdgcn_mfma_f32_16x16x32_bf16(ah[kt], bWhh[1][kt], a1,  0, 0, 0);
      aH2 = __builtin_amdgcn_mfma_f32_16x16x32_bf16(ah[kt], bWhh[2][kt], aH2, 0, 0, 0);
    }
    // stage X(v+2) into Xl[cur] (its X(v) consumed at step v-1)
    if (stg && v < 14) stageX(cur ? xdst1 : xdst0, v + 2);
    // lane-local GRU activation: (batch = q*4+reg, this j)
    #pragma unroll
    for (int reg = 0; reg < 4; ++reg) {
      float rr = fsig(a0[reg] + bs0);
      float zz = fsig(a1[reg] + bs1);
      float nn = ftanh(gcur[2][reg] + bi2 + rr*(aH2[reg] + bh2));
      float hnew = (1.f - zz)*nn + zz*hf[reg];
      hf[reg] = hnew;
      hb[nxt][ktw][q*4 + reg][kkw] = (short)f2bf(hnew);
    }
    ldsbar();   // hb(nxt) + Xl[cur] visible for step v+1
  };

  #pragma unroll 1
  for (int v2 = 0; v2 < 8; ++v2) {
    step(2*v2,     giA, giB);
    step(2*v2 + 1, giB, giA);
  }

  #pragma unroll
  for (int reg = 0; reg < 4; ++reg)
    vh[((size_t)run*16 + q*4 + reg)*D_ + j] = hf[reg];
}

// =====================================================================
// head v4 (pe fused) — verified, unchanged.
// =====================================================================
__global__ __launch_bounds__(256) void k_head(
    const float* __restrict__ vh, const float* __restrict__ Wp,
    const float* __restrict__ bp, float* __restrict__ out)
{
  const int o = blockIdx.x;
  const int tid = threadIdx.x;
  const int b = tid & 15, kc = tid >> 4;
  const int a1[7] = {0,1,2,3,4,8,9};
  const int a2[7] = {-1,5,6,7,-1,-1,-1};
  const float4* wb = (const float4*)(Wp + (size_t)o*896 + kc*56);
  float acc = 0.f;
  #pragma unroll
  for (int i = 0; i < 14; ++i) {
    int cc2 = kc*56 + i*4;
    int s = cc2 >> 7, d0 = cc2 & 127;
    float4 a = *(const float4*)(vh + (a1[s]*16 + b)*D_ + d0);
    int s2 = a2[s];
    if (s2 >= 0) {
      float4 a2v = *(const float4*)(vh + (s2*16 + b)*D_ + d0);
      a.x += a2v.x; a.y += a2v.y; a.z += a2v.z; a.w += a2v.w;
    }
    a.x = fmaxf(a.x, 0.f); a.y = fmaxf(a.y, 0.f);
    a.z = fmaxf(a.z, 0.f); a.w = fmaxf(a.w, 0.f);
    float4 ww = wb[i];
    acc += a.x*ww.x + a.y*ww.y + a.z*ww.z + a.w*ww.w;
  }
  __shared__ float red[16][17];
  red[kc][b] = acc;
  __syncthreads();
  if (tid < 16) {
    float s = 0.f;
    #pragma unroll
    for (int k = 0; k < 16; ++k) s += red[k][tid];
    out[tid*OUT_ + o] = s + bp[o];
  }
}

// =====================================================================
extern "C" void kernel_launch(void* const* d_in, const int* in_sizes, int n_in,
                              void* d_out, int out_size, void* d_ws, size_t ws_size,
                              hipStream_t stream)
{
  (void)in_sizes; (void)n_in; (void)out_size; (void)ws_size;
  const int*   cc   = (const int*)  d_in[0];
  const int*   cp   = (const int*)  d_in[1];
  const int*   cd   = (const int*)  d_in[2];
  const int*   cli  = (const int*)  d_in[3];
  const int*   clv  = (const int*)  d_in[4];
  const int*   cii  = (const int*)  d_in[5];
  const int*   civ  = (const int*)  d_in[6];
  const float* wgt  = (const float*)d_in[7];
  const float* age  = (const float*)d_in[8];
  const float* ec   = (const float*)d_in[9];
  const float* ep   = (const float*)d_in[10];
  const float* ed   = (const float*)d_in[11];
  const float* eli  = (const float*)d_in[12];
  const float* elv  = (const float*)d_in[13];
  const float* eii  = (const float*)d_in[14];
  const float* eiv  = (const float*)d_in[15];
  const float* mWih = (const float*)d_in[16];
  const float* mWhh = (const float*)d_in[17];
  const float* mbih = (const float*)d_in[18];
  const float* mbhh = (const float*)d_in[19];
  const float* vWih = (const float*)d_in[20];
  const float* vWhh = (const float*)d_in[21];
  const float* vbih = (const float*)d_in[22];
  const float* vbhh = (const float*)d_in[23];
  const float* Wself= (const float*)d_in[24];
  const float* Wmsg = (const float*)d_in[25];
  const float* fwW  = (const float*)d_in[26];
  const float* fwB  = (const float*)d_in[27];
  const float* faW  = (const float*)d_in[28];
  const float* faB  = (const float*)d_in[29];
  const float* Wp   = (const float*)d_in[30];
  const float* bp   = (const float*)d_in[31];
  float* out = (float*)d_out;
  float* ws  = (float*)d_ws;

  short* visb  = (short*)(ws + OFF_VISB);
  short* monb  = (short*)(ws + OFF_MONB);
  short* w12t  = (short*)(ws + OFF_W12T);
  short* wihb  = (short*)(ws + OFF_WIHB);
  float* xe    = ws + OFF_XE;
  float* last  = ws + OFF_LAST;
  float* vh    = ws + OFF_VH;

  k_prepvis<<<10816, 256, 0, stream>>>(Wself, Wmsg, mWih, wgt, age,
                                       fwW, fwB, faW, faB,
                                       cc, cp, cd, ec, ep, ed,
                                       cli, clv, cii, civ, eli, elv, eii, eiv,
                                       w12t, wihb, xe, visb, monb);
  k_ggru<<<128, 512, 0, stream>>>(monb, visb, w12t, wihb, Wself,
                                  mWhh, mbih, mbhh, last);
  k_vgru<<<10, 512, 0, stream>>>(last, xe, vWih, vWhh, vbih, vbhh, vh);
  k_head<<<600, 256, 0, stream>>>(vh, Wp, bp, out);
}